// Round 2
// 213.263 us; speedup vs baseline: 1.0093x; 1.0093x over previous
//
#include <hip/hip_runtime.h>
#include <cstdint>

#define KK 16384   // C*T
#define EE 256     // output features
#define M_USED 1792
#define LRELU_ALPHA 0.2f

typedef __bf16 bf16x8 __attribute__((ext_vector_type(8)));
typedef float f32x4 __attribute__((ext_vector_type(4)));

// ws layout (bytes):
//   [0, 8 MB)                 : Wt bf16 [256][16384]      (o-major, k-contiguous)
//   [WT, WT + nkc*0.92 MB)    : partial f16 [nkc][256][1792]
//   [after part, +1.84 MB)    : Wh f32 [256][1792]
#define WT_BYTES (256u*16384u*2u)

__device__ __forceinline__ unsigned short f2bf(float f){
  union { float f; unsigned u; } x; x.f = f;
  unsigned r = x.u + 0x7fffu + ((x.u >> 16) & 1u);
  return (unsigned short)(r >> 16);
}

// ---------------- Kernel 1: W (16384x256 f32) -> Wt (256x16384 bf16) ----------------
__global__ __launch_bounds__(256) void k_transpose_w(const float* __restrict__ W,
                                                     unsigned short* __restrict__ Wt){
  __shared__ float tile[64][65];
  const int i0 = blockIdx.x * 64;
  const int o0 = blockIdx.y * 64;
  const int tid = threadIdx.x;
  #pragma unroll
  for (int r = 0; r < 16; ++r){
    int il = r*4 + (tid >> 6);
    int ol = tid & 63;
    tile[il][ol] = W[(size_t)(i0+il)*EE + o0 + ol];
  }
  __syncthreads();
  #pragma unroll
  for (int r = 0; r < 16; ++r){
    int ol = r*4 + (tid >> 6);
    int il = tid & 63;
    Wt[(size_t)(o0+ol)*KK + i0 + il] = f2bf(tile[il][ol]);
  }
}

// ---------------- Kernel 2: pipelined GEMM ----------------
// D[o][m] = sum_k Wt[o][k] * hf[m][k].  BK=128 (2 c-planes)/iter, h prefetched
// one iter ahead into VGPRs, LDS double-buffered, ONE barrier per iter.
// 1-D grid 32*nkc, XCD-swizzled so same-kc blocks share an XCD's L2 (Wt slice
// = 512 KB -> 2 slices/XCD = 1 MB, L2-resident). 512 thr (8 waves); wave w
// owns o-rows [w*32, w*32+32). Partials stored fp16 (halves RT traffic;
// fp16 eps 5e-4 on partial std ~0.5 is far below existing bf16 GEMM error).
__global__ __launch_bounds__(512, 4) void k_gemm(const float* __restrict__ h,
                                                 const unsigned short* __restrict__ Wt,
                                                 _Float16* __restrict__ part,
                                                 int cpp /* c-planes per kc chunk */){
  __shared__ unsigned short Bs[2][64*136];   // m x k tile, stride 136 (16B-aligned rows)
  const int tid  = threadIdx.x;
  // bijective XCD swizzle: dispatch id -> work id; XCD j gets contiguous kc range
  const int nper = gridDim.x >> 3;           // blocks per XCD (gridDim.x % 8 == 0)
  const int id   = blockIdx.x;
  const int wid  = (id & 7)*nper + (id >> 3);
  const int mt   = wid & 31;
  const int kc   = wid >> 5;
  const int n0   = mt * 8;
  const int w    = tid >> 6;
  const int lane = tid & 63;
  const int col  = lane & 15;
  const int quad = lane >> 4;

  // zero pad rows (m = 56..63) in both buffers once
  for (int idx = tid; idx < 1088; idx += 512){
    Bs[0][7616 + idx] = 0;
    Bs[1][7616 + idx] = 0;
  }

  // h staging map: 2 planes x 8 n-rows x 112 float4 = 1792 float4 / 512 thr
  int ghb[4]; short hlds[4][4];
  const bool hv3 = (tid < 256);              // it=3 valid only for tid<256
  #pragma unroll
  for (int it = 0; it < 4; ++it){
    int j  = tid + it*512;
    if (j >= 1792) j = 0;
    int p  = j / 896;
    int jj = j - p*896;
    int nn = jj / 112;
    int f  = jj - nn*112;
    ghb[it] = (n0+nn)*114688 + p*448 + f*4;   // + cbase*448 later
    #pragma unroll
    for (int e = 0; e < 4; ++e){
      int rr = f*4 + e;
      int t_ = rr / 7;
      int v_ = rr - t_*7;
      hlds[it][e] = (short)((nn*7 + v_)*136 + p*64 + t_);
    }
  }

  // A-frag base: row (w*32 + oi*16 + col), 16B at k-offset quad*8
  const unsigned short* aptr = Wt + (size_t)(w*32 + col)*KK + quad*8;

  f32x4 acc[2][4];
  #pragma unroll
  for (int a_ = 0; a_ < 2; ++a_)
    #pragma unroll
    for (int b_ = 0; b_ < 4; ++b_)
      acc[a_][b_] = (f32x4){0.f, 0.f, 0.f, 0.f};

  const int c0    = kc * cpp;      // first c-plane of this chunk
  const int iters = cpp >> 1;      // 2 planes per iteration

  // prologue: h loads for s=0
  float4 hreg[4];
  {
    const int cb = c0*448;
    #pragma unroll
    for (int it = 0; it < 4; ++it)
      if (it < 3 || hv3)
        hreg[it] = *reinterpret_cast<const float4*>(h + (size_t)(ghb[it] + cb));
  }

  int buf = 0;
  for (int s = 0; s < iters; ++s){
    // 1. drain h prefetch into LDS buffer `buf`
    #pragma unroll
    for (int it = 0; it < 4; ++it){
      if (it < 3 || hv3){
        Bs[buf][hlds[it][0]] = f2bf(hreg[it].x);
        Bs[buf][hlds[it][1]] = f2bf(hreg[it].y);
        Bs[buf][hlds[it][2]] = f2bf(hreg[it].z);
        Bs[buf][hlds[it][3]] = f2bf(hreg[it].w);
      }
    }
    // 2. issue A-frag loads for THIS iteration (L2-resident, consumed after barrier)
    const int kb = (c0 + 2*s)*64;
    bf16x8 af[2][4];
    #pragma unroll
    for (int oi = 0; oi < 2; ++oi)
      #pragma unroll
      for (int kh = 0; kh < 4; ++kh)
        af[oi][kh] = *reinterpret_cast<const bf16x8*>(aptr + (size_t)oi*16*KK + kb + kh*32);
    // 3. issue h prefetch for NEXT iteration (HBM latency hidden by step 5)
    if (s + 1 < iters){
      const int cb = (c0 + 2*(s+1))*448;
      #pragma unroll
      for (int it = 0; it < 4; ++it)
        if (it < 3 || hv3)
          hreg[it] = *reinterpret_cast<const float4*>(h + (size_t)(ghb[it] + cb));
    }
    // 4. barrier: Bs[buf] now visible to all waves
    __syncthreads();
    // 5. MFMA over BK=128
    #pragma unroll
    for (int kh = 0; kh < 4; ++kh){
      bf16x8 bfr[4];
      #pragma unroll
      for (int mi = 0; mi < 4; ++mi)
        bfr[mi] = *reinterpret_cast<const bf16x8*>(&Bs[buf][(mi*16 + col)*136 + kh*32 + quad*8]);
      #pragma unroll
      for (int oi = 0; oi < 2; ++oi)
        #pragma unroll
        for (int mi = 0; mi < 4; ++mi)
          acc[oi][mi] = __builtin_amdgcn_mfma_f32_16x16x32_bf16(af[oi][kh], bfr[mi], acc[oi][mi], 0, 0, 0);
    }
    buf ^= 1;
  }

  // partials (fp16): part[kc][o][mt*56 + ml], ml < 56 (coalesced, masked tail)
  #pragma unroll
  for (int oi = 0; oi < 2; ++oi){
    #pragma unroll
    for (int r = 0; r < 4; ++r){
      int o = w*32 + oi*16 + quad*4 + r;
      size_t rowbase = ((size_t)(kc*256 + o))*M_USED + mt*56;
      #pragma unroll
      for (int mi = 0; mi < 4; ++mi){
        int ml = mi*16 + col;
        if (ml < 56) part[rowbase + ml] = (_Float16)acc[oi][mi][r];
      }
    }
  }
}

// ---------------- Kernel 3: reduce fp16 partials over kc (coalesced in m) ----------------
__global__ __launch_bounds__(256) void k_reduce(const _Float16* __restrict__ part,
                                                float* __restrict__ Wh, int nkc){
  const int m = blockIdx.x*256 + threadIdx.x;
  const int o = blockIdx.y;
  float s = 0.f;
  for (int k = 0; k < nkc; ++k)
    s += (float)part[((size_t)(k*256 + o))*M_USED + m];
  Wh[(size_t)o*M_USED + m] = s;
}

// ---------------- Kernel 4: attention + elu (adj-norm folded in) ----------------
__global__ __launch_bounds__(256) void k_attn(const float* __restrict__ Wh,
                                              const float* __restrict__ a,
                                              const float* __restrict__ Bp,
                                              float* __restrict__ out){
  const int n    = blockIdx.x;
  const int tid  = threadIdx.x;
  const int lane = tid & 63;
  const int wv   = tid >> 6;

  __shared__ float adjn[49];
  __shared__ float red1[4][7], red2[4][7];
  __shared__ float s1s[7], s2s[7];
  __shared__ float att0[49], att[49];

  if (tid == 0){
    float adj[49];
    float mn = 1e30f, mx = -1e30f;
    for (int i = 0; i < 7; ++i)
      for (int j = 0; j < 7; ++j){
        float x = Bp[i*7+j] + 1e-6f + (i == j ? 1.f : 0.f);
        adj[i*7+j] = x;
        mn = fminf(mn, x); mx = fmaxf(mx, x);
      }
    float inv = 1.f / (mx - mn);
    for (int i = 0; i < 49; ++i) adj[i] = (adj[i] - mn) * inv;
    float d12[7];
    for (int i = 0; i < 7; ++i){
      float s = 0.f;
      for (int j = 0; j < 7; ++j) s += adj[i*7+j];
      d12[i] = 1.f / sqrtf(s);
    }
    for (int i = 0; i < 7; ++i)
      for (int j = 0; j < 7; ++j)
        adjn[i*7+j] = d12[i] * adj[i*7+j] * d12[j];
  }

  float wh[7];
  #pragma unroll
  for (int v = 0; v < 7; ++v)
    wh[v] = Wh[(size_t)tid*M_USED + n*7 + v];

  const float a1 = a[tid];
  const float a2 = a[256 + tid];

  #pragma unroll
  for (int v = 0; v < 7; ++v){
    float x1 = wh[v]*a1;
    float x2 = wh[v]*a2;
    #pragma unroll
    for (int off = 32; off > 0; off >>= 1){
      x1 += __shfl_down(x1, off);
      x2 += __shfl_down(x2, off);
    }
    if (lane == 0){ red1[wv][v] = x1; red2[wv][v] = x2; }
  }
  __syncthreads();
  if (tid < 7){
    s1s[tid] = red1[0][tid]+red1[1][tid]+red1[2][tid]+red1[3][tid];
    s2s[tid] = red2[0][tid]+red2[1][tid]+red2[2][tid]+red2[3][tid];
  }
  __syncthreads();
  if (tid < 7){
    const int v = tid;
    float e[7]; float mx = -1e30f;
    #pragma unroll
    for (int u = 0; u < 7; ++u){
      float t = s1s[v] + s2s[u];
      t = t > 0.f ? t : LRELU_ALPHA*t;
      e[u] = t; mx = fmaxf(mx, t);
    }
    float sum = 0.f;
    #pragma unroll
    for (int u = 0; u < 7; ++u){ e[u] = expf(e[u]-mx); sum += e[u]; }
    float inv = 1.f/sum;
    #pragma unroll
    for (int u = 0; u < 7; ++u) att0[v*7+u] = e[u]*inv;
  }
  __syncthreads();
  if (tid < 7){
    const int v = tid;
    #pragma unroll
    for (int u = 0; u < 7; ++u){
      float s = 0.f;
      #pragma unroll
      for (int w7 = 0; w7 < 7; ++w7) s += adjn[v*7+w7]*att0[w7*7+u];
      att[v*7+u] = s;
    }
  }
  __syncthreads();
  #pragma unroll
  for (int v = 0; v < 7; ++v){
    float hp = 0.f;
    #pragma unroll
    for (int u = 0; u < 7; ++u) hp += att[v*7+u]*wh[u];
    float o = hp > 0.f ? hp : expm1f(hp);
    out[(size_t)(n*7+v)*256 + tid] = o;
  }
}

extern "C" void kernel_launch(void* const* d_in, const int* in_sizes, int n_in,
                              void* d_out, int out_size, void* d_ws, size_t ws_size,
                              hipStream_t stream){
  const float* h  = (const float*)d_in[0];
  const float* W  = (const float*)d_in[1];
  const float* a  = (const float*)d_in[2];
  const float* Bp = (const float*)d_in[3];
  float* out = (float*)d_out;
  char* ws = (char*)d_ws;

  const size_t part_elems = (size_t)256 * M_USED;                      // per kchunk
  const size_t need16 = WT_BYTES + 16 * part_elems * 2 + part_elems * 4;  // ~24.9 MB
  const int nkc = (ws_size >= need16) ? 16 : 8;

  unsigned short* Wt   = (unsigned short*)ws;
  _Float16*       part = (_Float16*)(ws + WT_BYTES);
  float*          Wh   = (float*)(ws + WT_BYTES + (size_t)nkc * part_elems * 2);

  k_transpose_w<<<dim3(256, 4), 256, 0, stream>>>(W, Wt);
  k_gemm<<<dim3(32 * nkc), 512, 0, stream>>>(h, Wt, part, 256/nkc);
  k_reduce<<<dim3(7, 256), 256, 0, stream>>>(part, Wh, nkc);
  k_attn<<<256, 256, 0, stream>>>(Wh, a, Bp, out);
}

// Round 3
// 210.773 us; speedup vs baseline: 1.0212x; 1.0118x over previous
//
#include <hip/hip_runtime.h>
#include <cstdint>

#define KK 16384   // C*T
#define EE 256     // output features
#define M_USED 1792
#define LRELU_ALPHA 0.2f

typedef __bf16 bf16x8 __attribute__((ext_vector_type(8)));
typedef float f32x4 __attribute__((ext_vector_type(4)));
typedef _Float16 f16x4 __attribute__((ext_vector_type(4)));

// ws layout (bytes):
//   [0, 8 MB)                 : Wt bf16 [256][16384]      (o-major, k-contiguous)
//   [WT, WT + nkc*0.92 MB)    : partial f16 [nkc][1792 m][256 o]  (o-contiguous!)
#define WT_BYTES (256u*16384u*2u)

__device__ __forceinline__ unsigned short f2bf(float f){
  union { float f; unsigned u; } x; x.f = f;
  unsigned r = x.u + 0x7fffu + ((x.u >> 16) & 1u);
  return (unsigned short)(r >> 16);
}

// ---------------- Kernel 1: W (16384x256 f32) -> Wt (256x16384 bf16) ----------------
__global__ __launch_bounds__(256) void k_transpose_w(const float* __restrict__ W,
                                                     unsigned short* __restrict__ Wt){
  __shared__ float tile[64][65];
  const int i0 = blockIdx.x * 64;
  const int o0 = blockIdx.y * 64;
  const int tid = threadIdx.x;
  #pragma unroll
  for (int r = 0; r < 16; ++r){
    int il = r*4 + (tid >> 6);
    int ol = tid & 63;
    tile[il][ol] = W[(size_t)(i0+il)*EE + o0 + ol];
  }
  __syncthreads();
  #pragma unroll
  for (int r = 0; r < 16; ++r){
    int ol = r*4 + (tid >> 6);
    int il = tid & 63;
    Wt[(size_t)(o0+ol)*KK + i0 + il] = f2bf(tile[il][ol]);
  }
}

// ---------------- Kernel 2: pipelined GEMM ----------------
// D[o][m] = sum_k Wt[o][k] * hf[m][k].  BK=128 (2 c-planes)/iter, h prefetched
// one iter ahead into VGPRs, LDS double-buffered, ONE barrier per iter.
// 1-D grid 32*nkc, XCD-swizzled so same-kc blocks share an XCD's L2 (Wt slice
// = 512 KB -> 2 slices/XCD = 1 MB, L2-resident). 512 thr (8 waves); wave w
// owns o-rows [w*32, w*32+32).
// Partials stored fp16 in [kc][m][o] layout: each lane's 4 acc rows are
// o-contiguous -> one 8B f16x4 store (8 stores/thread vs 32), and the
// consumer (k_attn) reads o-coalesced. No separate reduce kernel.
__global__ __launch_bounds__(512, 4) void k_gemm(const float* __restrict__ h,
                                                 const unsigned short* __restrict__ Wt,
                                                 _Float16* __restrict__ part,
                                                 int cpp /* c-planes per kc chunk */){
  __shared__ unsigned short Bs[2][64*136];   // m x k tile, stride 136 (16B-aligned rows)
  const int tid  = threadIdx.x;
  // bijective XCD swizzle: dispatch id -> work id; XCD j gets contiguous kc range
  const int nper = gridDim.x >> 3;           // blocks per XCD (gridDim.x % 8 == 0)
  const int id   = blockIdx.x;
  const int wid  = (id & 7)*nper + (id >> 3);
  const int mt   = wid & 31;
  const int kc   = wid >> 5;
  const int n0   = mt * 8;
  const int w    = tid >> 6;
  const int lane = tid & 63;
  const int col  = lane & 15;
  const int quad = lane >> 4;

  // zero pad rows (m = 56..63) in both buffers once
  for (int idx = tid; idx < 1088; idx += 512){
    Bs[0][7616 + idx] = 0;
    Bs[1][7616 + idx] = 0;
  }

  // h staging map: 2 planes x 8 n-rows x 112 float4 = 1792 float4 / 512 thr
  int ghb[4]; short hlds[4][4];
  const bool hv3 = (tid < 256);              // it=3 valid only for tid<256
  #pragma unroll
  for (int it = 0; it < 4; ++it){
    int j  = tid + it*512;
    if (j >= 1792) j = 0;
    int p  = j / 896;
    int jj = j - p*896;
    int nn = jj / 112;
    int f  = jj - nn*112;
    ghb[it] = (n0+nn)*114688 + p*448 + f*4;   // + cbase*448 later
    #pragma unroll
    for (int e = 0; e < 4; ++e){
      int rr = f*4 + e;
      int t_ = rr / 7;
      int v_ = rr - t_*7;
      hlds[it][e] = (short)((nn*7 + v_)*136 + p*64 + t_);
    }
  }

  // A-frag base: row (w*32 + oi*16 + col), 16B at k-offset quad*8
  const unsigned short* aptr = Wt + (size_t)(w*32 + col)*KK + quad*8;

  f32x4 acc[2][4];
  #pragma unroll
  for (int a_ = 0; a_ < 2; ++a_)
    #pragma unroll
    for (int b_ = 0; b_ < 4; ++b_)
      acc[a_][b_] = (f32x4){0.f, 0.f, 0.f, 0.f};

  const int c0    = kc * cpp;      // first c-plane of this chunk
  const int iters = cpp >> 1;      // 2 planes per iteration

  // prologue: h loads for s=0
  float4 hreg[4];
  {
    const int cb = c0*448;
    #pragma unroll
    for (int it = 0; it < 4; ++it)
      if (it < 3 || hv3)
        hreg[it] = *reinterpret_cast<const float4*>(h + (size_t)(ghb[it] + cb));
  }

  int buf = 0;
  for (int s = 0; s < iters; ++s){
    // 1. drain h prefetch into LDS buffer `buf`
    #pragma unroll
    for (int it = 0; it < 4; ++it){
      if (it < 3 || hv3){
        Bs[buf][hlds[it][0]] = f2bf(hreg[it].x);
        Bs[buf][hlds[it][1]] = f2bf(hreg[it].y);
        Bs[buf][hlds[it][2]] = f2bf(hreg[it].z);
        Bs[buf][hlds[it][3]] = f2bf(hreg[it].w);
      }
    }
    // 2. issue A-frag loads for THIS iteration (L2-resident, consumed after barrier)
    const int kb = (c0 + 2*s)*64;
    bf16x8 af[2][4];
    #pragma unroll
    for (int oi = 0; oi < 2; ++oi)
      #pragma unroll
      for (int kh = 0; kh < 4; ++kh)
        af[oi][kh] = *reinterpret_cast<const bf16x8*>(aptr + (size_t)oi*16*KK + kb + kh*32);
    // 3. issue h prefetch for NEXT iteration (HBM latency hidden by step 5)
    if (s + 1 < iters){
      const int cb = (c0 + 2*(s+1))*448;
      #pragma unroll
      for (int it = 0; it < 4; ++it)
        if (it < 3 || hv3)
          hreg[it] = *reinterpret_cast<const float4*>(h + (size_t)(ghb[it] + cb));
    }
    // 4. barrier: Bs[buf] now visible to all waves
    __syncthreads();
    // 5. MFMA over BK=128
    #pragma unroll
    for (int kh = 0; kh < 4; ++kh){
      bf16x8 bfr[4];
      #pragma unroll
      for (int mi = 0; mi < 4; ++mi)
        bfr[mi] = *reinterpret_cast<const bf16x8*>(&Bs[buf][(mi*16 + col)*136 + kh*32 + quad*8]);
      #pragma unroll
      for (int oi = 0; oi < 2; ++oi)
        #pragma unroll
        for (int mi = 0; mi < 4; ++mi)
          acc[oi][mi] = __builtin_amdgcn_mfma_f32_16x16x32_bf16(af[oi][kh], bfr[mi], acc[oi][mi], 0, 0, 0);
    }
    buf ^= 1;
  }

  // partials (fp16, [kc][m][o]): lane's 4 acc regs are o-contiguous -> f16x4 store.
  // m = mt*56 + mi*16 + col (mask <56), o = w*32 + oi*16 + quad*4.
  #pragma unroll
  for (int oi = 0; oi < 2; ++oi){
    const int ob = w*32 + oi*16 + quad*4;
    #pragma unroll
    for (int mi = 0; mi < 4; ++mi){
      int ml = mi*16 + col;
      if (ml < 56){
        size_t idx = ((size_t)kc*M_USED + mt*56 + ml)*256 + ob;
        f16x4 v;
        v[0] = (_Float16)acc[oi][mi][0];
        v[1] = (_Float16)acc[oi][mi][1];
        v[2] = (_Float16)acc[oi][mi][2];
        v[3] = (_Float16)acc[oi][mi][3];
        *reinterpret_cast<f16x4*>(part + idx) = v;
      }
    }
  }
}

// ---------------- Kernel 3: attention + elu (kc-reduction + adj-norm folded in) ----------------
// wh[v] = sum_kc part[kc][n*7+v][tid]  -- o-coalesced loads, LLC-resident,
// same summation order as the old k_reduce (bitwise-identical input).
__global__ __launch_bounds__(256) void k_attn(const _Float16* __restrict__ part,
                                              const float* __restrict__ a,
                                              const float* __restrict__ Bp,
                                              float* __restrict__ out, int nkc){
  const int n    = blockIdx.x;
  const int tid  = threadIdx.x;
  const int lane = tid & 63;
  const int wv   = tid >> 6;

  __shared__ float adjn[49];
  __shared__ float red1[4][7], red2[4][7];
  __shared__ float s1s[7], s2s[7];
  __shared__ float att0[49], att[49];

  if (tid == 0){
    float adj[49];
    float mn = 1e30f, mx = -1e30f;
    for (int i = 0; i < 7; ++i)
      for (int j = 0; j < 7; ++j){
        float x = Bp[i*7+j] + 1e-6f + (i == j ? 1.f : 0.f);
        adj[i*7+j] = x;
        mn = fminf(mn, x); mx = fmaxf(mx, x);
      }
    float inv = 1.f / (mx - mn);
    for (int i = 0; i < 49; ++i) adj[i] = (adj[i] - mn) * inv;
    float d12[7];
    for (int i = 0; i < 7; ++i){
      float s = 0.f;
      for (int j = 0; j < 7; ++j) s += adj[i*7+j];
      d12[i] = 1.f / sqrtf(s);
    }
    for (int i = 0; i < 7; ++i)
      for (int j = 0; j < 7; ++j)
        adjn[i*7+j] = d12[i] * adj[i*7+j] * d12[j];
  }

  // fused kc-reduction: coalesced in tid (=o)
  float wh[7];
  #pragma unroll
  for (int v = 0; v < 7; ++v) wh[v] = 0.f;
  for (int kc = 0; kc < nkc; ++kc){
    const _Float16* p = part + ((size_t)kc*M_USED + n*7)*256 + tid;
    #pragma unroll
    for (int v = 0; v < 7; ++v)
      wh[v] += (float)p[(size_t)v*256];
  }

  const float a1 = a[tid];
  const float a2 = a[256 + tid];

  #pragma unroll
  for (int v = 0; v < 7; ++v){
    float x1 = wh[v]*a1;
    float x2 = wh[v]*a2;
    #pragma unroll
    for (int off = 32; off > 0; off >>= 1){
      x1 += __shfl_down(x1, off);
      x2 += __shfl_down(x2, off);
    }
    if (lane == 0){ red1[wv][v] = x1; red2[wv][v] = x2; }
  }
  __syncthreads();
  if (tid < 7){
    s1s[tid] = red1[0][tid]+red1[1][tid]+red1[2][tid]+red1[3][tid];
    s2s[tid] = red2[0][tid]+red2[1][tid]+red2[2][tid]+red2[3][tid];
  }
  __syncthreads();
  if (tid < 7){
    const int v = tid;
    float e[7]; float mx = -1e30f;
    #pragma unroll
    for (int u = 0; u < 7; ++u){
      float t = s1s[v] + s2s[u];
      t = t > 0.f ? t : LRELU_ALPHA*t;
      e[u] = t; mx = fmaxf(mx, t);
    }
    float sum = 0.f;
    #pragma unroll
    for (int u = 0; u < 7; ++u){ e[u] = expf(e[u]-mx); sum += e[u]; }
    float inv = 1.f/sum;
    #pragma unroll
    for (int u = 0; u < 7; ++u) att0[v*7+u] = e[u]*inv;
  }
  __syncthreads();
  if (tid < 7){
    const int v = tid;
    #pragma unroll
    for (int u = 0; u < 7; ++u){
      float s = 0.f;
      #pragma unroll
      for (int w7 = 0; w7 < 7; ++w7) s += adjn[v*7+w7]*att0[w7*7+u];
      att[v*7+u] = s;
    }
  }
  __syncthreads();
  #pragma unroll
  for (int v = 0; v < 7; ++v){
    float hp = 0.f;
    #pragma unroll
    for (int u = 0; u < 7; ++u) hp += att[v*7+u]*wh[u];
    float o = hp > 0.f ? hp : expm1f(hp);
    out[(size_t)(n*7+v)*256 + tid] = o;
  }
}

extern "C" void kernel_launch(void* const* d_in, const int* in_sizes, int n_in,
                              void* d_out, int out_size, void* d_ws, size_t ws_size,
                              hipStream_t stream){
  const float* h  = (const float*)d_in[0];
  const float* W  = (const float*)d_in[1];
  const float* a  = (const float*)d_in[2];
  const float* Bp = (const float*)d_in[3];
  float* out = (float*)d_out;
  char* ws = (char*)d_ws;

  const size_t part_elems = (size_t)256 * M_USED;           // per kchunk
  const size_t need16 = WT_BYTES + 16 * part_elems * 2;     // ~22.7 MB
  const int nkc = (ws_size >= need16) ? 16 : 8;

  unsigned short* Wt   = (unsigned short*)ws;
  _Float16*       part = (_Float16*)(ws + WT_BYTES);

  k_transpose_w<<<dim3(256, 4), 256, 0, stream>>>(W, Wt);
  k_gemm<<<dim3(32 * nkc), 512, 0, stream>>>(h, Wt, part, 256/nkc);
  k_attn<<<256, 256, 0, stream>>>(part, a, Bp, out, nkc);
}